// Round 1
// baseline (1446.398 us; speedup 1.0000x reference)
//
#include <hip/hip_runtime.h>
#include <math.h>

#define N 2048
#define D 128
#define R 43
#define SPLIT 8

// ---------------- K0: head/tail vectors ----------------
__global__ __launch_bounds__(256) void k_headtail(
    const float* __restrict__ inputs,
    const float* __restrict__ w_head, const float* __restrict__ b_head,
    const float* __restrict__ w_tail, const float* __restrict__ b_tail,
    float* __restrict__ head, float* __restrict__ tail)
{
    int i = blockIdx.x * 256 + threadIdx.x;
    const float* row = inputs + (size_t)i * D;
    float h = 0.f, tl = 0.f;
    #pragma unroll 8
    for (int k = 0; k < D; ++k) {
        float x = row[k];
        h  += x * w_head[k];
        tl += x * w_tail[k];
    }
    head[i] = h  + b_head[0];
    tail[i] = tl + b_tail[0];
}

// ---------------- K1: s[i][j] = rel(i,j,:)*w + b + head[i] + tail[j] + mask ----
// Each block handles 256 consecutive (i,j) pairs = 11008 contiguous floats.
// Stage via coalesced float4 into LDS, then per-thread dot from LDS.
__global__ __launch_bounds__(256) void k_scores(
    const float* __restrict__ rel, const float* __restrict__ rel_mask,
    const float* __restrict__ w_rel, const float* __restrict__ b_rel,
    const float* __restrict__ head, const float* __restrict__ tail,
    float* __restrict__ s)
{
    __shared__ float lds[256 * R];          // 44032 B
    const int t = threadIdx.x;
    const size_t pair0 = (size_t)blockIdx.x * 256;
    const float* chunk = rel + pair0 * R;   // 44032-byte aligned
    const float4* c4 = (const float4*)chunk;
    #pragma unroll
    for (int k = 0; k < 10; ++k) {          // 10*256 float4 = 10240 floats
        float4 v = c4[k * 256 + t];
        ((float4*)lds)[k * 256 + t] = v;
    }
    #pragma unroll
    for (int k = 0; k < 3; ++k)             // remaining 768 floats
        lds[10240 + k * 256 + t] = chunk[10240 + k * 256 + t];
    __syncthreads();

    float acc = b_rel[0];
    #pragma unroll
    for (int r = 0; r < R; ++r)             // stride-43 LDS reads: 2-way alias, free
        acc += lds[t * R + r] * w_rel[r];   // w_rel[r]: uniform scalar loads

    size_t p = pair0 + t;
    int i = (int)(p >> 11);
    int j = (int)(p & (N - 1));
    s[p] = acc + head[i] + tail[j] + rel_mask[p];
}

// ---------------- K2: per-column (axis=0) softmax stats ----------------
__global__ __launch_bounds__(256) void k_colstats(
    const float* __restrict__ s, float* __restrict__ m, float* __restrict__ rl)
{
    int j = blockIdx.x * 256 + threadIdx.x;   // one column per thread, coalesced
    float mx = -1e30f;
    for (int i = 0; i < N; ++i)
        mx = fmaxf(mx, s[(size_t)i * N + j]);
    float sum = 0.f;
    for (int i = 0; i < N; ++i)
        sum += __expf(s[(size_t)i * N + j] - mx);
    m[j]  = mx;
    rl[j] = 1.0f / sum;
}

// ---------------- K3: out_part = exp(s - m) * (inputs * rl), split-K over j ----
// Block = 64 out-rows x 128 cols; grid = 32 row-blocks x SPLIT j-splits = 256.
__global__ __launch_bounds__(256) void k_agg(
    const float* __restrict__ s, const float* __restrict__ inputs,
    const float* __restrict__ m, const float* __restrict__ rl,
    float* __restrict__ part)
{
    __shared__ float bt[64 * D];        // 32 KB: inputs tile, pre-scaled by rl[j]
    __shared__ float at[64 * 65];       // 16.25 KB: exp tile, padded stride 65
    const int t  = threadIdx.x;
    const int i0 = (blockIdx.x & 31) * 64;
    const int sp = blockIdx.x >> 5;
    const int tr = t >> 4;              // 0..15 -> rows tr*4 .. tr*4+3
    const int tc = t & 15;              // cols tc*8 .. tc*8+7
    float acc[4][8];
    #pragma unroll
    for (int a = 0; a < 4; ++a)
        #pragma unroll
        for (int b = 0; b < 8; ++b) acc[a][b] = 0.f;

    for (int tt = 0; tt < 4; ++tt) {    // 4 tiles of BK=64 over this split's 256 j's
        const int j0 = sp * 256 + tt * 64;
        #pragma unroll
        for (int k = 0; k < 8; ++k) {   // stage bt: 2048 float4, coalesced
            int idx4 = k * 256 + t;
            int jj = idx4 >> 5, d4 = idx4 & 31;
            float4 v = *(const float4*)&inputs[(size_t)(j0 + jj) * D + d4 * 4];
            float sc = rl[j0 + jj];
            v.x *= sc; v.y *= sc; v.z *= sc; v.w *= sc;
            *(float4*)&bt[idx4 * 4] = v;
        }
        #pragma unroll
        for (int k = 0; k < 16; ++k) {  // stage at: 64x64 exp values, coalesced s read
            int idx = k * 256 + t;
            int r = idx >> 6, jj = idx & 63;
            float sv = s[(size_t)(i0 + r) * N + j0 + jj];
            at[r * 65 + jj] = __expf(sv - m[j0 + jj]);
        }
        __syncthreads();
        for (int jj = 0; jj < 64; ++jj) {
            float4 x = *(float4*)&bt[jj * D + tc * 8];
            float4 y = *(float4*)&bt[jj * D + tc * 8 + 4];
            #pragma unroll
            for (int rr = 0; rr < 4; ++rr) {
                float a = at[(tr * 4 + rr) * 65 + jj];
                acc[rr][0] += a * x.x; acc[rr][1] += a * x.y;
                acc[rr][2] += a * x.z; acc[rr][3] += a * x.w;
                acc[rr][4] += a * y.x; acc[rr][5] += a * y.y;
                acc[rr][6] += a * y.z; acc[rr][7] += a * y.w;
            }
        }
        __syncthreads();
    }
    #pragma unroll
    for (int rr = 0; rr < 4; ++rr) {
        size_t o = ((size_t)sp * N + i0 + tr * 4 + rr) * D + tc * 8;
        *(float4*)&part[o]     = make_float4(acc[rr][0], acc[rr][1], acc[rr][2], acc[rr][3]);
        *(float4*)&part[o + 4] = make_float4(acc[rr][4], acc[rr][5], acc[rr][6], acc[rr][7]);
    }
}

// ---------------- K4: reduce SPLIT partials ----------------
__global__ __launch_bounds__(256) void k_reduce(
    const float* __restrict__ part, float* __restrict__ out)
{
    int idx = blockIdx.x * 256 + threadIdx.x;   // float4 index, 65536 total
    float4 v = make_float4(0.f, 0.f, 0.f, 0.f);
    #pragma unroll
    for (int sp = 0; sp < SPLIT; ++sp) {
        float4 p = *(const float4*)&part[(size_t)sp * N * D + (size_t)idx * 4];
        v.x += p.x; v.y += p.y; v.z += p.z; v.w += p.w;
    }
    *(float4*)&out[(size_t)idx * 4] = v;
}

extern "C" void kernel_launch(void* const* d_in, const int* in_sizes, int n_in,
                              void* d_out, int out_size, void* d_ws, size_t ws_size,
                              hipStream_t stream) {
    const float* inputs   = (const float*)d_in[0];
    const float* relation = (const float*)d_in[1];
    const float* rel_mask = (const float*)d_in[2];
    const float* w_rel    = (const float*)d_in[3];
    const float* b_rel    = (const float*)d_in[4];
    const float* w_head   = (const float*)d_in[5];
    const float* b_head   = (const float*)d_in[6];
    const float* w_tail   = (const float*)d_in[7];
    const float* b_tail   = (const float*)d_in[8];
    float* out = (float*)d_out;

    // ws layout (floats): s[N*N] | head[N] | tail[N] | m[N] | rl[N] | part[SPLIT*N*D]
    float* ws   = (float*)d_ws;
    float* s    = ws;
    float* head = ws + (size_t)N * N;
    float* tail = head + N;
    float* m    = tail + N;
    float* rl   = m + N;
    float* part = rl + N;   // 16-byte aligned: (N*N + 4N)*4 bytes

    k_headtail<<<N / 256, 256, 0, stream>>>(inputs, w_head, b_head, w_tail, b_tail, head, tail);
    k_scores<<<(N * N) / 256, 256, 0, stream>>>(relation, rel_mask, w_rel, b_rel, head, tail, s);
    k_colstats<<<N / 256, 256, 0, stream>>>(s, m, rl);
    k_agg<<<32 * SPLIT, 256, 0, stream>>>(s, inputs, m, rl, part);
    k_reduce<<<(N * D / 4) / 256, 256, 0, stream>>>(part, out);
}

// Round 2
// 972.367 us; speedup vs baseline: 1.4875x; 1.4875x over previous
//
#include <hip/hip_runtime.h>
#include <math.h>

#define N 2048
#define D 128
#define R 43
#define SPLIT 8
#define CHUNKS 32   // row-chunks for column-softmax stats

typedef const __attribute__((address_space(1))) void* as1_cptr;
typedef __attribute__((address_space(3))) void* as3_ptr;

// ---------------- K0: head/tail vectors (4 lanes per row, float4) ----------------
__global__ __launch_bounds__(256) void k_headtail(
    const float* __restrict__ inputs,
    const float* __restrict__ w_head, const float* __restrict__ b_head,
    const float* __restrict__ w_tail, const float* __restrict__ b_tail,
    float* __restrict__ head, float* __restrict__ tail)
{
    const int t = threadIdx.x;
    const int row = blockIdx.x * 64 + (t >> 2);
    const int q = t & 3;                       // quarter of the row (32 floats)
    const float4* rp = (const float4*)(inputs + (size_t)row * D + q * 32);
    const float4* wh = (const float4*)(w_head + q * 32);
    const float4* wt = (const float4*)(w_tail + q * 32);
    float h = 0.f, tl = 0.f;
    #pragma unroll
    for (int k = 0; k < 8; ++k) {
        float4 v = rp[k];
        float4 a = wh[k];
        float4 b = wt[k];
        h  += v.x * a.x + v.y * a.y + v.z * a.z + v.w * a.w;
        tl += v.x * b.x + v.y * b.y + v.z * b.z + v.w * b.w;
    }
    h  += __shfl_xor(h, 1);  h  += __shfl_xor(h, 2);
    tl += __shfl_xor(tl, 1); tl += __shfl_xor(tl, 2);
    if (q == 0) {
        head[row] = h  + b_head[0];
        tail[row] = tl + b_tail[0];
    }
}

// ---------------- K1: s[i][j] = rel(i,j,:)*w + b + head[i] + tail[j] + mask ----
// Async global->LDS staging (identity byte copy), then per-thread dot from LDS.
__global__ __launch_bounds__(256) void k_scores(
    const float* __restrict__ rel, const float* __restrict__ rel_mask,
    const float* __restrict__ w_rel, const float* __restrict__ b_rel,
    const float* __restrict__ head, const float* __restrict__ tail,
    float* __restrict__ s)
{
    __shared__ float lds[256 * R];          // 44032 B
    const int t = threadIdx.x;
    const int lane = t & 63;
    const int wave = t >> 6;
    const size_t pair0 = (size_t)blockIdx.x * 256;
    const char* chunk = (const char*)(rel + pair0 * R);   // 44032-B aligned
    char* lbase = (char*)lds;

    // wave w stages bytes [w*11008, (w+1)*11008): 10 x 1KB (size16) + 3 x 256B (size4)
    const int wb = wave * 11008;
    #pragma unroll
    for (int k = 0; k < 10; ++k) {
        __builtin_amdgcn_global_load_lds(
            (as1_cptr)(chunk + wb + k * 1024 + lane * 16),
            (as3_ptr)(lbase + wb + k * 1024),
            16, 0, 0);
    }
    #pragma unroll
    for (int k = 0; k < 3; ++k) {
        __builtin_amdgcn_global_load_lds(
            (as1_cptr)(chunk + wb + 10240 + k * 256 + lane * 4),
            (as3_ptr)(lbase + wb + 10240 + k * 256),
            4, 0, 0);
    }
    __syncthreads();   // compiler drains vmcnt before s_barrier

    float acc = b_rel[0];
    #pragma unroll
    for (int r = 0; r < R; ++r)             // stride-43 LDS reads: 2-way alias, free
        acc += lds[t * R + r] * w_rel[r];

    size_t p = pair0 + t;
    int i = (int)(p >> 11);
    int j = (int)(p & (N - 1));
    s[p] = acc + head[i] + tail[j] + rel_mask[p];
}

// ---------------- K2a: per-column partial (max, sumexp) over a 64-row chunk ----
__global__ __launch_bounds__(256) void k_colstats_part(
    const float* __restrict__ s, float* __restrict__ mpart, float* __restrict__ lpart)
{
    const int j = (blockIdx.x & 7) * 256 + threadIdx.x;   // column, coalesced
    const int c = blockIdx.x >> 3;                        // row chunk 0..31
    const int i0 = c * 64;
    float mx = -1e30f;
    for (int i = i0; i < i0 + 64; ++i)
        mx = fmaxf(mx, s[(size_t)i * N + j]);
    float sum = 0.f;
    for (int i = i0; i < i0 + 64; ++i)
        sum += __expf(s[(size_t)i * N + j] - mx);         // 2nd pass: L1/L2 hits
    mpart[c * N + j] = mx;
    lpart[c * N + j] = sum;
}

// ---------------- K2b: combine 32 chunk partials -> m, 1/l ----------------
__global__ __launch_bounds__(256) void k_colstats_comb(
    const float* __restrict__ mpart, const float* __restrict__ lpart,
    float* __restrict__ m, float* __restrict__ rl)
{
    const int j = blockIdx.x * 256 + threadIdx.x;
    float mx = -1e30f;
    #pragma unroll 8
    for (int c = 0; c < CHUNKS; ++c)
        mx = fmaxf(mx, mpart[c * N + j]);
    float sum = 0.f;
    #pragma unroll 8
    for (int c = 0; c < CHUNKS; ++c)
        sum += lpart[c * N + j] * __expf(mpart[c * N + j] - mx);
    m[j]  = mx;
    rl[j] = 1.0f / sum;
}

// ---------------- K3: out_part = exp(s - m) * (inputs * rl), split-K over j ----
__global__ __launch_bounds__(256) void k_agg(
    const float* __restrict__ s, const float* __restrict__ inputs,
    const float* __restrict__ m, const float* __restrict__ rl,
    float* __restrict__ part)
{
    __shared__ float bt[64 * D];        // 32 KB: inputs tile, pre-scaled by rl[j]
    __shared__ float at[64 * 65];       // 16.25 KB: exp tile, padded stride 65
    const int t  = threadIdx.x;
    const int i0 = (blockIdx.x & 31) * 64;
    const int sp = blockIdx.x >> 5;
    const int tr = t >> 4;              // rows tr*4 .. tr*4+3
    const int tc = t & 15;              // cols tc*8 .. tc*8+7
    float acc[4][8];
    #pragma unroll
    for (int a = 0; a < 4; ++a)
        #pragma unroll
        for (int b = 0; b < 8; ++b) acc[a][b] = 0.f;

    for (int tt = 0; tt < 4; ++tt) {
        const int j0 = sp * 256 + tt * 64;
        #pragma unroll
        for (int k = 0; k < 8; ++k) {
            int idx4 = k * 256 + t;
            int jj = idx4 >> 5, d4 = idx4 & 31;
            float4 v = *(const float4*)&inputs[(size_t)(j0 + jj) * D + d4 * 4];
            float sc = rl[j0 + jj];
            v.x *= sc; v.y *= sc; v.z *= sc; v.w *= sc;
            *(float4*)&bt[idx4 * 4] = v;
        }
        #pragma unroll
        for (int k = 0; k < 16; ++k) {
            int idx = k * 256 + t;
            int r = idx >> 6, jj = idx & 63;
            float sv = s[(size_t)(i0 + r) * N + j0 + jj];
            at[r * 65 + jj] = __expf(sv - m[j0 + jj]);
        }
        __syncthreads();
        for (int jj = 0; jj < 64; ++jj) {
            float4 x = *(float4*)&bt[jj * D + tc * 8];
            float4 y = *(float4*)&bt[jj * D + tc * 8 + 4];
            #pragma unroll
            for (int rr = 0; rr < 4; ++rr) {
                float a = at[(tr * 4 + rr) * 65 + jj];
                acc[rr][0] += a * x.x; acc[rr][1] += a * x.y;
                acc[rr][2] += a * x.z; acc[rr][3] += a * x.w;
                acc[rr][4] += a * y.x; acc[rr][5] += a * y.y;
                acc[rr][6] += a * y.z; acc[rr][7] += a * y.w;
            }
        }
        __syncthreads();
    }
    #pragma unroll
    for (int rr = 0; rr < 4; ++rr) {
        size_t o = ((size_t)sp * N + i0 + tr * 4 + rr) * D + tc * 8;
        *(float4*)&part[o]     = make_float4(acc[rr][0], acc[rr][1], acc[rr][2], acc[rr][3]);
        *(float4*)&part[o + 4] = make_float4(acc[rr][4], acc[rr][5], acc[rr][6], acc[rr][7]);
    }
}

// ---------------- K4: reduce SPLIT partials ----------------
__global__ __launch_bounds__(256) void k_reduce(
    const float* __restrict__ part, float* __restrict__ out)
{
    int idx = blockIdx.x * 256 + threadIdx.x;
    float4 v = make_float4(0.f, 0.f, 0.f, 0.f);
    #pragma unroll
    for (int sp = 0; sp < SPLIT; ++sp) {
        float4 p = *(const float4*)&part[(size_t)sp * N * D + (size_t)idx * 4];
        v.x += p.x; v.y += p.y; v.z += p.z; v.w += p.w;
    }
    *(float4*)&out[(size_t)idx * 4] = v;
}

extern "C" void kernel_launch(void* const* d_in, const int* in_sizes, int n_in,
                              void* d_out, int out_size, void* d_ws, size_t ws_size,
                              hipStream_t stream) {
    const float* inputs   = (const float*)d_in[0];
    const float* relation = (const float*)d_in[1];
    const float* rel_mask = (const float*)d_in[2];
    const float* w_rel    = (const float*)d_in[3];
    const float* b_rel    = (const float*)d_in[4];
    const float* w_head   = (const float*)d_in[5];
    const float* b_head   = (const float*)d_in[6];
    const float* w_tail   = (const float*)d_in[7];
    const float* b_tail   = (const float*)d_in[8];
    float* out = (float*)d_out;

    // ws (floats): s[N*N] | head[N] | tail[N] | m[N] | rl[N] | part[SPLIT*N*D]
    //            | mpart[CHUNKS*N] | lpart[CHUNKS*N]
    float* ws    = (float*)d_ws;
    float* s     = ws;
    float* head  = ws + (size_t)N * N;
    float* tail  = head + N;
    float* m     = tail + N;
    float* rl    = m + N;
    float* part  = rl + N;
    float* mpart = part + (size_t)SPLIT * N * D;
    float* lpart = mpart + (size_t)CHUNKS * N;

    k_headtail<<<N / 64, 256, 0, stream>>>(inputs, w_head, b_head, w_tail, b_tail, head, tail);
    k_scores<<<(N * N) / 256, 256, 0, stream>>>(relation, rel_mask, w_rel, b_rel, head, tail, s);
    k_colstats_part<<<8 * CHUNKS, 256, 0, stream>>>(s, mpart, lpart);
    k_colstats_comb<<<N / 256, 256, 0, stream>>>(mpart, lpart, m, rl);
    k_agg<<<32 * SPLIT, 256, 0, stream>>>(s, inputs, m, rl, part);
    k_reduce<<<(N * D / 4) / 256, 256, 0, stream>>>(part, out);
}